// Round 16
// baseline (33.395 us; speedup 1.0000x reference)
//
#include <hip/hip_runtime.h>
#include <hip/hip_fp16.h>

// ---------------------------------------------------------------------------
// PodNetClassifier: out[b][c] = sum_k simi*softmax_k(simi),
//   simi[b,c,k] = -max(2 - 2*dot(a_b, th_{c*10+k}), 0)  (unit vectors)
// Round 15: XCD-rectangle swizzle. R14 diagnostic: FETCH 95MB/rep (operand
// re-fetch: blocks sharing X/TH scattered over 8 XCDs, write stream flushes
// L2) + WRITE 102MB/rep (3x amp: adjacent 64B class-chunks of one cache line
// written by DIFFERENT XCDs under round-robin dispatch). Fix: grid 32x64=2048;
// xcd = bid&7 owns bn in [xcd*8, xcd*8+8). Per-XCD L2 working set = 160KB TH
// slice + 32KB X band; adjacent bn = same XCD adjacent dispatch -> write
// chunks merge into full lines. Compute structure = R13 (packed-f16 score
// math, division-free G, MFMA-as-reducer softmax, laundered counted vmcnt,
// zero LDS, zero barriers).
// ---------------------------------------------------------------------------

#define BATCH   8192
#define DIM     64
#define KPROX   10
#define NCLASS  1000
#define NCOL    (NCLASS * KPROX)   // 10000
#define NBTILE  (BATCH / 16)       // 512 x-row tiles
#define NNTILE  (NCOL / 16)        // 625 proxy tiles (0..624)

#define NBM     32                 // row blocks (256 rows each)
#define NBNP    64                 // padded class groups (last group fully masked)
#define XBLKS   (NBTILE / 4)         // 128 prep blocks for x
#define TBLKS   ((NCOL + 255) / 256) // 40 prep blocks for theta

typedef __attribute__((ext_vector_type(8))) short bf16x8;
typedef __attribute__((ext_vector_type(4))) float f32x4;
typedef __attribute__((ext_vector_type(2))) unsigned int u32x2;
typedef __attribute__((ext_vector_type(4))) __fp16 f16x4;
typedef __attribute__((ext_vector_type(2))) _Float16 h16x2;
typedef __attribute__((ext_vector_type(4))) _Float16 h16x4;

#define LOG2E 1.4426950408889634f
#define LN2   0.6931471805599453f

__device__ inline unsigned short f32_to_bf16(float f) {
    unsigned int u = __float_as_uint(f);
    u += 0x7FFFu + ((u >> 16) & 1u);   // round-to-nearest-even
    return (unsigned short)(u >> 16);
}

// non-rematerializable 16B load (issue only; caller handles vmcnt)
__device__ inline bf16x8 gload16(const unsigned short* p) {
    bf16x8 r;
    asm volatile("global_load_dwordx4 %0, %1, off" : "=v"(r) : "v"(p));
    return r;
}
// laundered wait: defines S0/S1 -> consumers get a data edge to this wait
#define WVM(N, S0, S1) \
    asm volatile("s_waitcnt vmcnt(" #N ")" : "+v"(S0), "+v"(S1) :: "memory")

// ---- merged prep: blocks [0,128) pack x, blocks [128,168) pack theta -------
// X planes: Xf_p[(bt*64 + lane)*8 + i] = a[bt*16 + (lane&15)][p*32 + (lane>>4)*8 + i]
// TH planes: same fragment layout over proxy rows j = c*10+kk (tile j>>4, row j&15).
__global__ __launch_bounds__(256)
void prep_kernel(const float* __restrict__ x, const float* __restrict__ theta,
                 unsigned short* __restrict__ Xf0, unsigned short* __restrict__ Xf1,
                 unsigned short* __restrict__ THf0, unsigned short* __restrict__ THf1) {
    if (blockIdx.x < XBLKS) {
        int wave = threadIdx.x >> 6, lane = threadIdx.x & 63;
        int bt  = blockIdx.x * 4 + wave;
        int r16 = lane & 15, hi = lane >> 4;
        const float* src = x + (size_t)(bt * 16 + r16) * DIM + hi * 8;
        f32x4 v0 = *(const f32x4*)(src);
        f32x4 v1 = *(const f32x4*)(src + 4);
        f32x4 v2 = *(const f32x4*)(src + 32);
        f32x4 v3 = *(const f32x4*)(src + 36);
        float ss = 0.f;
        #pragma unroll
        for (int i = 0; i < 4; ++i)
            ss += v0[i]*v0[i] + v1[i]*v1[i] + v2[i]*v2[i] + v3[i]*v3[i];
        ss += __shfl_xor(ss, 16);
        ss += __shfl_xor(ss, 32);
        float sc = __builtin_amdgcn_rsqf(ss);   // norms are O(8), no eps needed
        bf16x8 p0, p1;
        #pragma unroll
        for (int i = 0; i < 4; ++i) {
            p0[i]     = (short)f32_to_bf16(v0[i] * sc);
            p0[i + 4] = (short)f32_to_bf16(v1[i] * sc);
            p1[i]     = (short)f32_to_bf16(v2[i] * sc);
            p1[i + 4] = (short)f32_to_bf16(v3[i] * sc);
        }
        ((bf16x8*)Xf0)[bt * 64 + lane] = p0;
        ((bf16x8*)Xf1)[bt * 64 + lane] = p1;
    } else {
        int tid = (blockIdx.x - XBLKS) * 256 + threadIdx.x;
        if (tid >= NCOL) return;
        int kk = tid / NCLASS, c = tid - kk * NCLASS;  // consecutive tid -> consecutive c
        const float* src = theta + kk * NCLASS + c;
        float v[DIM];
        float ss = 0.f;
        #pragma unroll
        for (int d = 0; d < DIM; ++d) {
            v[d] = src[(size_t)d * NCOL];
            ss += v[d] * v[d];
        }
        float sc = __builtin_amdgcn_rsqf(ss);
        int j = c * KPROX + kk;
        int jt = j >> 4, jr = j & 15;
        #pragma unroll
        for (int h = 0; h < 8; ++h) {      // chunk h holds d = h*8 .. h*8+7
            unsigned short* dst = (h < 4 ? THf0 : THf1)
                                + ((size_t)jt * 64 + (h & 3) * 16 + jr) * 8;
            #pragma unroll
            for (int i = 0; i < 8; ++i)
                dst[i] = f32_to_bf16(v[h * 8 + i] * sc);
        }
    }
}

// ---- main: swapped-score MFMA + MFMA-reduced softmax, zero LDS -------------
__global__ __launch_bounds__(256, 4)
void podnet_main(const unsigned short* __restrict__ Xf0,
                 const unsigned short* __restrict__ Xf1,
                 const unsigned short* __restrict__ THf0,
                 const unsigned short* __restrict__ THf1,
                 float* __restrict__ out) {
    // XCD-rectangle decode: bid&7 = XCD (round-robin dispatch); each XCD owns
    // 8 adjacent bn columns; within XCD, bn sweeps fastest (write-line merge),
    // bm slow (32KB X band per 8 blocks, 160KB TH slice L2-resident).
    unsigned bid = blockIdx.x;
    int xcd = bid & 7;
    int idx = bid >> 3;                 // 0..255
    int bnw = idx & 7;                  // 0..7
    int bm  = idx >> 3;                 // 0..31
    int bn  = xcd * 8 + bnw;            // 0..63 (bn=63: all classes masked)
    int wave = threadIdx.x >> 6, lane = threadIdx.x & 63;
    int r16 = lane & 15, hi = lane >> 4;

    // TH tile address, tail-clamped (virtual tiles >=625 -> 624; their
    // proxies map to classes >= 1000, never matching an unmasked target)
    auto th0 = [&](int ct) {
        int ti = bn * 10 + ct;
        ti = ti > (NNTILE - 1) ? (NNTILE - 1) : ti;
        return THf0 + ((size_t)ti * 64 + lane) * 8;
    };
    auto th1 = [&](int ct) {
        int ti = bn * 10 + ct;
        ti = ti > (NNTILE - 1) ? (NNTILE - 1) : ti;
        return THf1 + ((size_t)ti * 64 + lane) * 8;
    };

    // ---- issue X fragments (8 loads), then the first three TH tile pairs ---
    const unsigned short* xp = Xf0 + ((size_t)(bm * 16 + wave * 4) * 64 + lane) * 8;
    const unsigned short* xq = Xf1 + ((size_t)(bm * 16 + wave * 4) * 64 + lane) * 8;
    bf16x8 xa0[4], xa1[4];
    #pragma unroll
    for (int rt = 0; rt < 4; ++rt) {
        xa0[rt] = gload16(xp + (size_t)rt * 64 * 8);
        xa1[rt] = gload16(xq + (size_t)rt * 64 * 8);
    }
    bf16x8 A0 = gload16(th0(0)), A1 = gload16(th1(0));
    bf16x8 B0 = gload16(th0(1)), B1 = gload16(th1(1));
    bf16x8 C0 = gload16(th0(2)), C1 = gload16(th1(2));

    f32x4 ps[4], ws[4];
    #pragma unroll
    for (int rt = 0; rt < 4; ++rt) {
        ps[rt] = (f32x4){0.f, 0.f, 0.f, 0.f};
        ws[rt] = (f32x4){0.f, 0.f, 0.f, 0.f};
    }

    int target = bn * 16 + r16;         // this lane's output class column
    int q0     = hi * 4 - 10 * r16;     // class test: (unsigned)(q0+16CT+j) < 10

    const h16x2 K2  = {(_Float16)(2.0f * LOG2E),  (_Float16)(2.0f * LOG2E)};
    const h16x2 KM2 = {(_Float16)(-2.0f * LOG2E), (_Float16)(-2.0f * LOG2E)};
    const h16x2 Z2  = {(_Float16)0.0f, (_Float16)0.0f};

    // Process one 16-proxy score tile: swapped MFMA + packed-f16 softmax math
    // + MFMA-reduce against the 0/1 class-membership fragment G.
    auto proc = [&](bf16x8 T0, bf16x8 T1, int CT) {
        int q = q0 + CT * 16;
        unsigned glo = ((unsigned)q       < 10u ? 0x3C00u     : 0u)
                     | ((unsigned)(q + 1) < 10u ? 0x3C000000u : 0u);
        unsigned ghi = ((unsigned)(q + 2) < 10u ? 0x3C00u     : 0u)
                     | ((unsigned)(q + 3) < 10u ? 0x3C000000u : 0u);
        u32x2 gu = {glo, ghi};
        f16x4 G = __builtin_bit_cast(f16x4, gu);
        #pragma unroll
        for (int rt = 0; rt < 4; ++rt) {
            // D1[proxy][xrow]: col(lane&15)=x-row, reg=proxy (A=TH, B=X)
            f32x4 d = {0.f, 0.f, 0.f, 0.f};
            d = __builtin_amdgcn_mfma_f32_16x16x32_bf16(T0, xa0[rt], d, 0, 0, 0);
            d = __builtin_amdgcn_mfma_f32_16x16x32_bf16(T1, xa1[rt], d, 0, 0, 0);
            // packed f16: y = min(d*2log2e - 2log2e, 0); e = 2^y; v = y*e
            h16x2 h01 = __builtin_bit_cast(h16x2, __builtin_amdgcn_cvt_pkrtz(d[0], d[1]));
            h16x2 h23 = __builtin_bit_cast(h16x2, __builtin_amdgcn_cvt_pkrtz(d[2], d[3]));
            h16x2 y01 = __builtin_elementwise_min(h16x2(h01 * K2 + KM2), Z2);
            h16x2 y23 = __builtin_elementwise_min(h16x2(h23 * K2 + KM2), Z2);
            h16x2 e01 = __builtin_bit_cast(h16x2, h2exp2(__builtin_bit_cast(__half2, y01)));
            h16x2 e23 = __builtin_bit_cast(h16x2, h2exp2(__builtin_bit_cast(__half2, y23)));
            h16x2 v01 = y01 * e01;
            h16x2 v23 = y23 * e23;
            h16x4 ef4 = __builtin_shufflevector(e01, e23, 0, 1, 2, 3);
            h16x4 vf4 = __builtin_shufflevector(v01, v23, 0, 1, 2, 3);
            // e/v are valid A-fragments (row=lane&15=xrow, k=hi*4+j=proxy)
            ps[rt] = __builtin_amdgcn_mfma_f32_16x16x16f16(
                         __builtin_bit_cast(f16x4, ef4), G, ps[rt], 0, 0, 0);
            ws[rt] = __builtin_amdgcn_mfma_f32_16x16x16f16(
                         __builtin_bit_cast(f16x4, vf4), G, ws[rt], 0, 0, 0);
        }
    };

    // 3-slot rotation over the 10 TH tiles, laundered counted vmcnt:
    // steady state keeps 3 tile-pairs in flight (vmcnt(4) = wait oldest pair)
    WVM(4, A0, A1);  proc(A0, A1, 0);  A0 = gload16(th0(3)); A1 = gload16(th1(3));
    WVM(4, B0, B1);  proc(B0, B1, 1);  B0 = gload16(th0(4)); B1 = gload16(th1(4));
    WVM(4, C0, C1);  proc(C0, C1, 2);  C0 = gload16(th0(5)); C1 = gload16(th1(5));
    WVM(4, A0, A1);  proc(A0, A1, 3);  A0 = gload16(th0(6)); A1 = gload16(th1(6));
    WVM(4, B0, B1);  proc(B0, B1, 4);  B0 = gload16(th0(7)); B1 = gload16(th1(7));
    WVM(4, C0, C1);  proc(C0, C1, 5);  C0 = gload16(th0(8)); C1 = gload16(th1(8));
    WVM(4, A0, A1);  proc(A0, A1, 6);  A0 = gload16(th0(9)); A1 = gload16(th1(9));
    WVM(4, B0, B1);  proc(B0, B1, 7);
    WVM(2, C0, C1);  proc(C0, C1, 8);
    WVM(0, A0, A1);  proc(A0, A1, 9);

    // epilogue: ps/ws C-layout col(lane&15)=class slot, reg=xrow (hi*4+r)
    bool ok = target < NCLASS;
    size_t row0 = (size_t)bm * 256 + wave * 64 + hi * 4;
    #pragma unroll
    for (int rt = 0; rt < 4; ++rt) {
        float* op = out + (row0 + rt * 16) * NCLASS + target;
        #pragma unroll
        for (int r = 0; r < 4; ++r) {
            float o = ws[rt][r] * __builtin_amdgcn_rcpf(ps[rt][r]) * LN2;
            if (ok) op[(size_t)r * NCLASS] = o;
        }
    }
}

extern "C" void kernel_launch(void* const* d_in, const int* in_sizes, int n_in,
                              void* d_out, int out_size, void* d_ws, size_t ws_size,
                              hipStream_t stream) {
    const float* x     = (const float*)d_in[0];   // (8192, 64)
    const float* theta = (const float*)d_in[1];   // (64, 10, 1000)
    float* out = (float*)d_out;                   // (8192, 1000) f32

    unsigned short* Xf0 = (unsigned short*)d_ws;       // 512 KB each X plane
    unsigned short* Xf1 = Xf0 + (size_t)NBTILE * 512;
    unsigned short* Tf0 = Xf1 + (size_t)NBTILE * 512;  // 640 KB each TH plane
    unsigned short* Tf1 = Tf0 + (size_t)NNTILE * 512;

    prep_kernel<<<XBLKS + TBLKS, 256, 0, stream>>>(x, theta, Xf0, Xf1, Tf0, Tf1);
    podnet_main<<<NBM * NBNP, 256, 0, stream>>>(Xf0, Xf1, Tf0, Tf1, out);
}

// Round 17
// 33.073 us; speedup vs baseline: 1.0097x; 1.0097x over previous
//
#include <hip/hip_runtime.h>
#include <hip/hip_fp16.h>

// ---------------------------------------------------------------------------
// PodNetClassifier: out[b][c] = sum_k simi*softmax_k(simi),
//   simi[b,c,k] = -max(2 - 2*dot(a_b, th_{c*10+k}), 0)  (unit vectors)
// Round 17: full-line vector stores via reduce-MFMA operand swap.
//   ps = mfma(G, e) (was mfma(e, G)): C-layout flips to col(lane&15)=x-row,
//   reg = 4 CONTIGUOUS class slots -> one aligned global_store_dwordx4 per
//   row-tile per thread; each 64B output line written wholly by one wave
//   instruction (no partial-line RMW, 4x fewer store instrs). G fragment is
//   UNCHANGED (A/B fragment layouts are symmetric; bn cancels in the
//   membership predicate). Dispatch reverted to bm-fastest (R9's measured
//   FETCH=5.6MB regime). Rest = R13: packed-f16 score math, division-free G,
//   laundered counted vmcnt, zero LDS, zero barriers.
// ---------------------------------------------------------------------------

#define BATCH   8192
#define DIM     64
#define KPROX   10
#define NCLASS  1000
#define NCOL    (NCLASS * KPROX)   // 10000
#define NBTILE  (BATCH / 16)       // 512 x-row tiles
#define NNTILE  (NCOL / 16)        // 625 proxy tiles (0..624)

#define NBM     32                 // row blocks (256 rows each)
#define NBN     63                 // class groups (16 classes = 160 proxies)
#define XBLKS   (NBTILE / 4)         // 128 prep blocks for x
#define TBLKS   ((NCOL + 255) / 256) // 40 prep blocks for theta

typedef __attribute__((ext_vector_type(8))) short bf16x8;
typedef __attribute__((ext_vector_type(4))) float f32x4;
typedef __attribute__((ext_vector_type(2))) unsigned int u32x2;
typedef __attribute__((ext_vector_type(4))) __fp16 f16x4;
typedef __attribute__((ext_vector_type(2))) _Float16 h16x2;
typedef __attribute__((ext_vector_type(4))) _Float16 h16x4;

#define LOG2E 1.4426950408889634f
#define LN2   0.6931471805599453f

__device__ inline unsigned short f32_to_bf16(float f) {
    unsigned int u = __float_as_uint(f);
    u += 0x7FFFu + ((u >> 16) & 1u);   // round-to-nearest-even
    return (unsigned short)(u >> 16);
}

// non-rematerializable 16B load (issue only; caller handles vmcnt)
__device__ inline bf16x8 gload16(const unsigned short* p) {
    bf16x8 r;
    asm volatile("global_load_dwordx4 %0, %1, off" : "=v"(r) : "v"(p));
    return r;
}
// laundered wait: defines S0/S1 -> consumers get a data edge to this wait
#define WVM(N, S0, S1) \
    asm volatile("s_waitcnt vmcnt(" #N ")" : "+v"(S0), "+v"(S1) :: "memory")

// ---- merged prep: blocks [0,128) pack x, blocks [128,168) pack theta -------
// X planes: Xf_p[(bt*64 + lane)*8 + i] = a[bt*16 + (lane&15)][p*32 + (lane>>4)*8 + i]
// TH planes: same fragment layout over proxy rows j = c*10+kk (tile j>>4, row j&15).
__global__ __launch_bounds__(256)
void prep_kernel(const float* __restrict__ x, const float* __restrict__ theta,
                 unsigned short* __restrict__ Xf0, unsigned short* __restrict__ Xf1,
                 unsigned short* __restrict__ THf0, unsigned short* __restrict__ THf1) {
    if (blockIdx.x < XBLKS) {
        int wave = threadIdx.x >> 6, lane = threadIdx.x & 63;
        int bt  = blockIdx.x * 4 + wave;
        int r16 = lane & 15, hi = lane >> 4;
        const float* src = x + (size_t)(bt * 16 + r16) * DIM + hi * 8;
        f32x4 v0 = *(const f32x4*)(src);
        f32x4 v1 = *(const f32x4*)(src + 4);
        f32x4 v2 = *(const f32x4*)(src + 32);
        f32x4 v3 = *(const f32x4*)(src + 36);
        float ss = 0.f;
        #pragma unroll
        for (int i = 0; i < 4; ++i)
            ss += v0[i]*v0[i] + v1[i]*v1[i] + v2[i]*v2[i] + v3[i]*v3[i];
        ss += __shfl_xor(ss, 16);
        ss += __shfl_xor(ss, 32);
        float sc = __builtin_amdgcn_rsqf(ss);   // norms are O(8), no eps needed
        bf16x8 p0, p1;
        #pragma unroll
        for (int i = 0; i < 4; ++i) {
            p0[i]     = (short)f32_to_bf16(v0[i] * sc);
            p0[i + 4] = (short)f32_to_bf16(v1[i] * sc);
            p1[i]     = (short)f32_to_bf16(v2[i] * sc);
            p1[i + 4] = (short)f32_to_bf16(v3[i] * sc);
        }
        ((bf16x8*)Xf0)[bt * 64 + lane] = p0;
        ((bf16x8*)Xf1)[bt * 64 + lane] = p1;
    } else {
        int tid = (blockIdx.x - XBLKS) * 256 + threadIdx.x;
        if (tid >= NCOL) return;
        int kk = tid / NCLASS, c = tid - kk * NCLASS;  // consecutive tid -> consecutive c
        const float* src = theta + kk * NCLASS + c;
        float v[DIM];
        float ss = 0.f;
        #pragma unroll
        for (int d = 0; d < DIM; ++d) {
            v[d] = src[(size_t)d * NCOL];
            ss += v[d] * v[d];
        }
        float sc = __builtin_amdgcn_rsqf(ss);
        int j = c * KPROX + kk;
        int jt = j >> 4, jr = j & 15;
        #pragma unroll
        for (int h = 0; h < 8; ++h) {      // chunk h holds d = h*8 .. h*8+7
            unsigned short* dst = (h < 4 ? THf0 : THf1)
                                + ((size_t)jt * 64 + (h & 3) * 16 + jr) * 8;
            #pragma unroll
            for (int i = 0; i < 8; ++i)
                dst[i] = f32_to_bf16(v[h * 8 + i] * sc);
        }
    }
}

// ---- main: swapped-score MFMA + MFMA-reduced softmax, zero LDS -------------
__global__ __launch_bounds__(256, 4)
void podnet_main(const unsigned short* __restrict__ Xf0,
                 const unsigned short* __restrict__ Xf1,
                 const unsigned short* __restrict__ THf0,
                 const unsigned short* __restrict__ THf1,
                 float* __restrict__ out) {
    unsigned bid = blockIdx.x;
    int bm  = bid & 31;                 // bm fastest: consecutive blocks share
    int bn  = bid >> 5;                 // the TH panel (R9: FETCH 5.6MB)
    int wave = threadIdx.x >> 6, lane = threadIdx.x & 63;
    int r16 = lane & 15, hi = lane >> 4;

    // TH tile address, tail-clamped (bn=62 virtual tiles 625..629 -> 624;
    // their proxies map to classes >= 1000, never matched by unmasked slots)
    auto th0 = [&](int ct) {
        int ti = bn * 10 + ct;
        ti = ti > (NNTILE - 1) ? (NNTILE - 1) : ti;
        return THf0 + ((size_t)ti * 64 + lane) * 8;
    };
    auto th1 = [&](int ct) {
        int ti = bn * 10 + ct;
        ti = ti > (NNTILE - 1) ? (NNTILE - 1) : ti;
        return THf1 + ((size_t)ti * 64 + lane) * 8;
    };

    // ---- issue X fragments (8 loads), then the first three TH tile pairs ---
    const unsigned short* xp = Xf0 + ((size_t)(bm * 16 + wave * 4) * 64 + lane) * 8;
    const unsigned short* xq = Xf1 + ((size_t)(bm * 16 + wave * 4) * 64 + lane) * 8;
    bf16x8 xa0[4], xa1[4];
    #pragma unroll
    for (int rt = 0; rt < 4; ++rt) {
        xa0[rt] = gload16(xp + (size_t)rt * 64 * 8);
        xa1[rt] = gload16(xq + (size_t)rt * 64 * 8);
    }
    bf16x8 A0 = gload16(th0(0)), A1 = gload16(th1(0));
    bf16x8 B0 = gload16(th0(1)), B1 = gload16(th1(1));
    bf16x8 C0 = gload16(th0(2)), C1 = gload16(th1(2));

    f32x4 ps[4], ws[4];
    #pragma unroll
    for (int rt = 0; rt < 4; ++rt) {
        ps[rt] = (f32x4){0.f, 0.f, 0.f, 0.f};
        ws[rt] = (f32x4){0.f, 0.f, 0.f, 0.f};
    }

    int q0 = hi * 4 - 10 * r16;     // class test: (unsigned)(q0+16CT+j) < 10
                                    // (same predicate for G-as-A: bn cancels)

    const h16x2 K2  = {(_Float16)(2.0f * LOG2E),  (_Float16)(2.0f * LOG2E)};
    const h16x2 KM2 = {(_Float16)(-2.0f * LOG2E), (_Float16)(-2.0f * LOG2E)};
    const h16x2 Z2  = {(_Float16)0.0f, (_Float16)0.0f};

    // Process one 16-proxy score tile: swapped MFMA + packed-f16 softmax math
    // + MFMA-reduce. Reduce order mfma(G, e): D col(lane&15)=xrow,
    // reg = contiguous class slots hi*4..hi*4+3 -> dwordx4 stores.
    auto proc = [&](bf16x8 T0, bf16x8 T1, int CT) {
        int q = q0 + CT * 16;
        unsigned glo = ((unsigned)q       < 10u ? 0x3C00u     : 0u)
                     | ((unsigned)(q + 1) < 10u ? 0x3C000000u : 0u);
        unsigned ghi = ((unsigned)(q + 2) < 10u ? 0x3C00u     : 0u)
                     | ((unsigned)(q + 3) < 10u ? 0x3C000000u : 0u);
        u32x2 gu = {glo, ghi};
        f16x4 G = __builtin_bit_cast(f16x4, gu);
        #pragma unroll
        for (int rt = 0; rt < 4; ++rt) {
            // D1[proxy][xrow]: col(lane&15)=x-row, reg=proxy (A=TH, B=X)
            f32x4 d = {0.f, 0.f, 0.f, 0.f};
            d = __builtin_amdgcn_mfma_f32_16x16x32_bf16(T0, xa0[rt], d, 0, 0, 0);
            d = __builtin_amdgcn_mfma_f32_16x16x32_bf16(T1, xa1[rt], d, 0, 0, 0);
            // packed f16: y = min(d*2log2e - 2log2e, 0); e = 2^y; v = y*e
            h16x2 h01 = __builtin_bit_cast(h16x2, __builtin_amdgcn_cvt_pkrtz(d[0], d[1]));
            h16x2 h23 = __builtin_bit_cast(h16x2, __builtin_amdgcn_cvt_pkrtz(d[2], d[3]));
            h16x2 y01 = __builtin_elementwise_min(h16x2(h01 * K2 + KM2), Z2);
            h16x2 y23 = __builtin_elementwise_min(h16x2(h23 * K2 + KM2), Z2);
            h16x2 e01 = __builtin_bit_cast(h16x2, h2exp2(__builtin_bit_cast(__half2, y01)));
            h16x2 e23 = __builtin_bit_cast(h16x2, h2exp2(__builtin_bit_cast(__half2, y23)));
            h16x2 v01 = y01 * e01;
            h16x2 v23 = y23 * e23;
            h16x4 ef4 = __builtin_shufflevector(e01, e23, 0, 1, 2, 3);
            h16x4 vf4 = __builtin_shufflevector(v01, v23, 0, 1, 2, 3);
            // e/v as B-fragment (col=lane&15=xrow, k=hi*4+j=proxy);
            // G as A-fragment (row=class slot, k=proxy) -- same bits as before
            ps[rt] = __builtin_amdgcn_mfma_f32_16x16x16f16(
                         G, __builtin_bit_cast(f16x4, ef4), ps[rt], 0, 0, 0);
            ws[rt] = __builtin_amdgcn_mfma_f32_16x16x16f16(
                         G, __builtin_bit_cast(f16x4, vf4), ws[rt], 0, 0, 0);
        }
    };

    // 3-slot rotation over the 10 TH tiles, laundered counted vmcnt:
    // steady state keeps 3 tile-pairs in flight (vmcnt(4) = wait oldest pair)
    WVM(4, A0, A1);  proc(A0, A1, 0);  A0 = gload16(th0(3)); A1 = gload16(th1(3));
    WVM(4, B0, B1);  proc(B0, B1, 1);  B0 = gload16(th0(4)); B1 = gload16(th1(4));
    WVM(4, C0, C1);  proc(C0, C1, 2);  C0 = gload16(th0(5)); C1 = gload16(th1(5));
    WVM(4, A0, A1);  proc(A0, A1, 3);  A0 = gload16(th0(6)); A1 = gload16(th1(6));
    WVM(4, B0, B1);  proc(B0, B1, 4);  B0 = gload16(th0(7)); B1 = gload16(th1(7));
    WVM(4, C0, C1);  proc(C0, C1, 5);  C0 = gload16(th0(8)); C1 = gload16(th1(8));
    WVM(4, A0, A1);  proc(A0, A1, 6);  A0 = gload16(th0(9)); A1 = gload16(th1(9));
    WVM(4, B0, B1);  proc(B0, B1, 7);
    WVM(2, C0, C1);  proc(C0, C1, 8);
    WVM(0, A0, A1);  proc(A0, A1, 9);

    // epilogue: D col(lane&15)=xrow (within tile), reg r = class slot hi*4+r.
    // One aligned dwordx4 per row-tile: out row = bm*256+wave*64+rt*16+r16,
    // classes bn*16 + hi*4 .. +3 (16B-aligned: row stride 4000 = 250*16).
    int col0 = bn * 16 + hi * 4;
    bool ok = col0 < NCLASS;            // 4-class chunk fully in/out (1000%4==0)
    size_t rowb = (size_t)bm * 256 + wave * 64 + r16;
    #pragma unroll
    for (int rt = 0; rt < 4; ++rt) {
        f32x4 o;
        #pragma unroll
        for (int r = 0; r < 4; ++r)
            o[r] = ws[rt][r] * __builtin_amdgcn_rcpf(ps[rt][r]) * LN2;
        if (ok) *(f32x4*)(out + (rowb + rt * 16) * NCLASS + col0) = o;
    }
}

extern "C" void kernel_launch(void* const* d_in, const int* in_sizes, int n_in,
                              void* d_out, int out_size, void* d_ws, size_t ws_size,
                              hipStream_t stream) {
    const float* x     = (const float*)d_in[0];   // (8192, 64)
    const float* theta = (const float*)d_in[1];   // (64, 10, 1000)
    float* out = (float*)d_out;                   // (8192, 1000) f32

    unsigned short* Xf0 = (unsigned short*)d_ws;       // 512 KB each X plane
    unsigned short* Xf1 = Xf0 + (size_t)NBTILE * 512;
    unsigned short* Tf0 = Xf1 + (size_t)NBTILE * 512;  // 640 KB each TH plane
    unsigned short* Tf1 = Tf0 + (size_t)NNTILE * 512;

    prep_kernel<<<XBLKS + TBLKS, 256, 0, stream>>>(x, theta, Xf0, Xf1, Tf0, Tf1);
    podnet_main<<<NBM * NBN, 256, 0, stream>>>(Xf0, Xf1, Tf0, Tf1, out);
}